// Round 1
// baseline (481.274 us; speedup 1.0000x reference)
//
#include <hip/hip_runtime.h>
#include <hip/hip_bf16.h>

typedef __bf16 bf16_t;
typedef __bf16 bf16x8 __attribute__((ext_vector_type(8)));
typedef float f32x4 __attribute__((ext_vector_type(4)));

#define NUM_USER 200000
#define NUM_ITEM 200000
#define DIM_E 64
#define DIM_FEAT 128
#define HID 256
#define BATCH 16384
#define GG 17
#define NN (BATCH * GG)   // 278528
#define NREP 139264       // int(NN * 0.5)

// ---------------------------------------------------------------------------
// K1: per-row inverse L2 norm of v_feat (wave per row) + zero the replace-mask
// ---------------------------------------------------------------------------
__global__ __launch_bounds__(256) void norm_mask_kernel(
    const float* __restrict__ vfeat, float* __restrict__ inv_norm,
    unsigned char* __restrict__ mask)
{
    const int wave = threadIdx.x >> 6;
    const int lane = threadIdx.x & 63;
    const int row  = blockIdx.x * 4 + wave;
    if (row < NUM_ITEM) {
        const float2 v = *reinterpret_cast<const float2*>(vfeat + (size_t)row * DIM_FEAT + lane * 2);
        float s = v.x * v.x + v.y * v.y;
#pragma unroll
        for (int off = 32; off > 0; off >>= 1) s += __shfl_xor(s, off, 64);
        if (lane == 0) inv_norm[row] = 1.0f / fmaxf(sqrtf(s), 1e-12f);
    }
    const int t = blockIdx.x * 256 + threadIdx.x;
    if (t < NN) mask[t] = 0;
}

// ---------------------------------------------------------------------------
// K2: transpose + bf16-cast weights (B-fragments want N-major), scatter mask
// ---------------------------------------------------------------------------
__global__ __launch_bounds__(256) void prep2_kernel(
    const float* __restrict__ W1, const float* __restrict__ W2,
    const int* __restrict__ rand_index,
    bf16_t* __restrict__ W1t, bf16_t* __restrict__ W2t,
    unsigned char* __restrict__ mask)
{
    const int t = blockIdx.x * 256 + threadIdx.x;
    if (t < HID * DIM_FEAT) {            // W1t[n][k], n<256, k<128
        const int n = t >> 7, k = t & 127;
        W1t[t] = (bf16_t)W1[k * HID + n];
    }
    if (t < DIM_E * HID) {               // W2t[n][k], n<64, k<256
        const int n = t >> 8, k = t & 255;
        W2t[t] = (bf16_t)W2[k * DIM_E + n];
    }
    if (t < NREP) mask[rand_index[t]] = 1;
}

// ---------------------------------------------------------------------------
// K3: fused MFMA encoder. One wave = one 16-row strip.
//   phase1: h(16x256) = leaky(vfn @ W1 + b1)  (K=128, 4 k-steps, 16 n-tiles)
//   LDS round-trip (C-layout -> A-layout), padded stride 264 (bank safety)
//   phase2: feature(16x64) = h @ W2 + b2      (K=256, 8 k-steps, 4 n-tiles)
// ---------------------------------------------------------------------------
__global__ __launch_bounds__(256) void encoder_kernel(
    const float* __restrict__ vfeat, const float* __restrict__ inv_norm,
    const bf16_t* __restrict__ W1t, const float* __restrict__ b1,
    const bf16_t* __restrict__ W2t, const float* __restrict__ b2v,
    float* __restrict__ feature)
{
    const int wave = threadIdx.x >> 6;
    const int lane = threadIdx.x & 63;
    const int m    = lane & 15;
    const int quad = lane >> 4;
    const int strip = blockIdx.x * 4 + wave;
    const int row0  = strip * 16;
    const int row   = row0 + m;

    __shared__ bf16_t h_lds[4][16][HID + 8];

    // A fragments for phase 1: vf[row][k], normalized, cast bf16
    const float inv = inv_norm[row];
    bf16x8 af[4];
#pragma unroll
    for (int ks = 0; ks < 4; ++ks) {
        const float4* ap = reinterpret_cast<const float4*>(
            vfeat + (size_t)row * DIM_FEAT + ks * 32 + quad * 8);
        const float4 a0 = ap[0];
        const float4 a1 = ap[1];
        bf16x8 v;
        v[0] = (bf16_t)(a0.x * inv); v[1] = (bf16_t)(a0.y * inv);
        v[2] = (bf16_t)(a0.z * inv); v[3] = (bf16_t)(a0.w * inv);
        v[4] = (bf16_t)(a1.x * inv); v[5] = (bf16_t)(a1.y * inv);
        v[6] = (bf16_t)(a1.z * inv); v[7] = (bf16_t)(a1.w * inv);
        af[ks] = v;
    }

    f32x4 acc[16];
#pragma unroll
    for (int nt = 0; nt < 16; ++nt) acc[nt] = (f32x4){0.f, 0.f, 0.f, 0.f};

#pragma unroll
    for (int nt = 0; nt < 16; ++nt) {
        const int n = nt * 16 + m;
        const bf16_t* bp = W1t + n * DIM_FEAT + quad * 8;
#pragma unroll
        for (int ks = 0; ks < 4; ++ks) {
            const bf16x8 bfrag = *reinterpret_cast<const bf16x8*>(bp + ks * 32);
            acc[nt] = __builtin_amdgcn_mfma_f32_16x16x32_bf16(af[ks], bfrag, acc[nt], 0, 0, 0);
        }
    }

    // bias + leaky_relu, store h strip to LDS as bf16
#pragma unroll
    for (int nt = 0; nt < 16; ++nt) {
        const int c = nt * 16 + m;
        const float bias = b1[c];
#pragma unroll
        for (int i = 0; i < 4; ++i) {
            const int r = quad * 4 + i;
            float hv = acc[nt][i] + bias;
            hv = hv >= 0.f ? hv : 0.01f * hv;
            h_lds[wave][r][c] = (bf16_t)hv;
        }
    }

    __syncthreads();

    // phase 2
    f32x4 acc2[4];
#pragma unroll
    for (int nt = 0; nt < 4; ++nt) acc2[nt] = (f32x4){0.f, 0.f, 0.f, 0.f};

#pragma unroll
    for (int ks = 0; ks < 8; ++ks) {
        const bf16x8 a2 = *reinterpret_cast<const bf16x8*>(&h_lds[wave][m][ks * 32 + quad * 8]);
#pragma unroll
        for (int nt = 0; nt < 4; ++nt) {
            const int n = nt * 16 + m;
            const bf16x8 bfrag = *reinterpret_cast<const bf16x8*>(W2t + n * HID + ks * 32 + quad * 8);
            acc2[nt] = __builtin_amdgcn_mfma_f32_16x16x32_bf16(a2, bfrag, acc2[nt], 0, 0, 0);
        }
    }

#pragma unroll
    for (int nt = 0; nt < 4; ++nt) {
        const int c = nt * 16 + m;
        const float bias = b2v[c];
#pragma unroll
        for (int i = 0; i < 4; ++i) {
            const int r = quad * 4 + i;
            feature[(size_t)(row0 + r) * DIM_E + c] = acc2[nt][i] + bias;
        }
    }
}

// ---------------------------------------------------------------------------
// K4: per-(b,g) element: gathers + 4 packed wave reductions + exp
// ---------------------------------------------------------------------------
__global__ __launch_bounds__(256) void loss_elem_kernel(
    const float* __restrict__ feature, const float* __restrict__ id_emb,
    const int* __restrict__ user_t, const int* __restrict__ item_t,
    const unsigned char* __restrict__ mask,
    float* __restrict__ s1, float* __restrict__ s2)
{
    const int wave = threadIdx.x >> 6;
    const int lane = threadIdx.x & 63;
    const int n = blockIdx.x * 4 + wave;
    const int b = n / GG;
    const int u   = user_t[n];
    const int it  = item_t[n];
    const int pos = item_t[b * GG];
    int fidx = it - NUM_USER;
    fidx = min(max(fidx, 0), NUM_ITEM - 1);

    const float fv = feature[(size_t)fidx * DIM_E + lane];
    const float ue = id_emb[(size_t)u * DIM_E + lane];
    const float pe = id_emb[(size_t)pos * DIM_E + lane];
    const float ae = mask[n] ? fv : id_emb[(size_t)it * DIM_E + lane];

    float rx = fv * fv;   // ||f||^2
    float ry = pe * pe;   // ||pe||^2
    float rz = pe * fv;   // pe . f
    float rw = ue * ae;   // ue . all_item_input
#pragma unroll
    for (int off = 32; off > 0; off >>= 1) {
        rx += __shfl_xor(rx, off, 64);
        ry += __shfl_xor(ry, off, 64);
        rz += __shfl_xor(rz, off, 64);
        rw += __shfl_xor(rw, off, 64);
    }
    if (lane == 0) {
        const float dot1 = rz / (fmaxf(sqrtf(rx), 1e-12f) * fmaxf(sqrtf(ry), 1e-12f));
        s1[n] = __expf(dot1 * 5.0f);   // 1/TEMP = 5
        s2[n] = __expf(rw * 5.0f);
    }
}

// ---------------------------------------------------------------------------
// K5: per-b softmax-style loss + block reduce -> 64 partials
// ---------------------------------------------------------------------------
__global__ __launch_bounds__(256) void loss_reduce_kernel(
    const float* __restrict__ s1, const float* __restrict__ s2,
    float* __restrict__ partials)
{
    const int b = blockIdx.x * 256 + threadIdx.x;  // 64*256 == 16384 exactly
    float tot1 = 0.f, tot2 = 0.f, p1 = 0.f, p2 = 0.f;
#pragma unroll
    for (int g = 0; g < GG; ++g) {
        const float a1 = s1[b * GG + g];
        const float a2 = s2[b * GG + g];
        if (g == 0) { p1 = a1; p2 = a2; }
        tot1 += a1; tot2 += a2;
    }
    const float l1 = -logf(p1 / (tot1 + 1e-8f) + 1e-8f);
    const float l2 = -logf(p2 / (tot2 + 1e-8f) + 1e-8f);
    float v = 0.5f * l1 + 0.5f * l2;
#pragma unroll
    for (int off = 32; off > 0; off >>= 1) v += __shfl_xor(v, off, 64);
    __shared__ float red[4];
    const int wave = threadIdx.x >> 6, lane = threadIdx.x & 63;
    if (lane == 0) red[wave] = v;
    __syncthreads();
    if (threadIdx.x == 0) partials[blockIdx.x] = red[0] + red[1] + red[2] + red[3];
}

__global__ __launch_bounds__(64) void final_kernel(
    const float* __restrict__ partials, float* __restrict__ out)
{
    float v = partials[threadIdx.x];
#pragma unroll
    for (int off = 32; off > 0; off >>= 1) v += __shfl_xor(v, off, 64);
    if (threadIdx.x == 0) out[0] = v * (1.0f / BATCH);
}

// ---------------------------------------------------------------------------
extern "C" void kernel_launch(void* const* d_in, const int* in_sizes, int n_in,
                              void* d_out, int out_size, void* d_ws, size_t ws_size,
                              hipStream_t stream)
{
    (void)in_sizes; (void)n_in; (void)out_size; (void)ws_size;
    const float* v_feat    = (const float*)d_in[0];
    const float* id_emb    = (const float*)d_in[1];
    const float* W1        = (const float*)d_in[2];
    const float* b1        = (const float*)d_in[3];
    const float* W2        = (const float*)d_in[4];
    const float* b2        = (const float*)d_in[5];
    const int*   user_t    = (const int*)d_in[6];
    const int*   item_t    = (const int*)d_in[7];
    const int*   rand_idx  = (const int*)d_in[8];

    char* ws = (char*)d_ws;
    float*         inv_norm = (float*)(ws + 0);              // 200000*4 -> pad 800256
    bf16_t*        W1t      = (bf16_t*)(ws + 800256);        // 256*128*2 = 65536
    bf16_t*        W2t      = (bf16_t*)(ws + 865792);        // 64*256*2  = 32768
    unsigned char* mask     = (unsigned char*)(ws + 898560); // 278528
    float*         s1       = (float*)(ws + 1177088);        // 278528*4
    float*         s2       = (float*)(ws + 2291200);        // 278528*4
    float*         partials = (float*)(ws + 3405312);        // 64*4 -> 256
    float*         feature  = (float*)(ws + 3405568);        // 200000*64*4 = 51.2MB

    norm_mask_kernel<<<50000, 256, 0, stream>>>(v_feat, inv_norm, mask);
    prep2_kernel<<<544, 256, 0, stream>>>(W1, W2, rand_idx, W1t, W2t, mask);
    encoder_kernel<<<3125, 256, 0, stream>>>(v_feat, inv_norm, W1t, b1, W2t, b2, feature);
    loss_elem_kernel<<<69632, 256, 0, stream>>>(feature, id_emb, user_t, item_t, mask, s1, s2);
    loss_reduce_kernel<<<64, 256, 0, stream>>>(s1, s2, partials);
    final_kernel<<<1, 64, 0, stream>>>(partials, (float*)d_out);
}

// Round 2
// 355.834 us; speedup vs baseline: 1.3525x; 1.3525x over previous
//
#include <hip/hip_runtime.h>
#include <hip/hip_bf16.h>

typedef __bf16 bf16_t;
typedef __bf16 bf16x8 __attribute__((ext_vector_type(8)));
typedef float f32x4 __attribute__((ext_vector_type(4)));

#define NUM_USER 200000
#define NUM_ITEM 200000
#define DIM_E 64
#define DIM_FEAT 128
#define HID 256
#define BATCH 16384
#define GG 17
#define NN (BATCH * GG)   // 278528
#define NREP 139264       // int(NN * 0.5)
#define HP 40             // LDS h-buffer pitch (32 cols used + 8 pad; keeps b128 reads 16B-aligned)

// ---------------------------------------------------------------------------
// K1: transpose + bf16-cast weights (B-fragments want N-major), scatter mask
// ---------------------------------------------------------------------------
__global__ __launch_bounds__(256) void prep2_kernel(
    const float* __restrict__ W1, const float* __restrict__ W2,
    const int* __restrict__ rand_index,
    bf16_t* __restrict__ W1t, bf16_t* __restrict__ W2t,
    unsigned char* __restrict__ mask)
{
    const int t = blockIdx.x * 256 + threadIdx.x;
    if (t < HID * DIM_FEAT) {            // W1t[n][k], n<256, k<128
        const int n = t >> 7, k = t & 127;
        W1t[t] = (bf16_t)W1[k * HID + n];
    }
    if (t < DIM_E * HID) {               // W2t[n][k], n<64, k<256
        const int n = t >> 8, k = t & 255;
        W2t[t] = (bf16_t)W2[k * DIM_E + n];
    }
    if (t < NREP) mask[rand_index[t]] = 1;
}

// ---------------------------------------------------------------------------
// K2: fused MFMA encoder v2. One wave = 64 rows (4 strips of 16).
//   - l2norm fused: sumsq from the A-load registers via shfl_xor(16),(32)
//   - B fragments loaded once per wave, reused across 4 strips (4x amortize)
//   - phase2 interleaved per 32-col h pair: LDS buffer only 64xHP bf16/wave,
//     wave-private (no __syncthreads anywhere)
// ---------------------------------------------------------------------------
__global__ __launch_bounds__(256, 2) void encoder2_kernel(
    const float* __restrict__ vfeat,
    const bf16_t* __restrict__ W1t, const float* __restrict__ b1v,
    const bf16_t* __restrict__ W2t, const float* __restrict__ b2v,
    float* __restrict__ feature)
{
    const int wave = threadIdx.x >> 6;
    const int lane = threadIdx.x & 63;
    const int m    = lane & 15;
    const int quad = lane >> 4;
    const int wid  = blockIdx.x * 4 + wave;

    __shared__ bf16_t hlds[4][64 * HP];

    if (wid >= 3125) return;             // 3125 * 64 == 200000, no barriers used
    const size_t row_base = (size_t)wid * 64;
    bf16_t* hw = hlds[wave];

    // ---- A fragments (normalized, bf16) for 4 strips: af[s][ks] ----
    bf16x8 af[4][4];
#pragma unroll
    for (int s = 0; s < 4; ++s) {
        const size_t row = row_base + s * 16 + m;
        const float* rp = vfeat + row * DIM_FEAT + quad * 8;
        float4 v0[4], v1[4];
#pragma unroll
        for (int ks = 0; ks < 4; ++ks) {
            v0[ks] = *reinterpret_cast<const float4*>(rp + ks * 32);
            v1[ks] = *reinterpret_cast<const float4*>(rp + ks * 32 + 4);
        }
        float ss = 0.f;
#pragma unroll
        for (int ks = 0; ks < 4; ++ks) {
            ss += v0[ks].x * v0[ks].x + v0[ks].y * v0[ks].y
                + v0[ks].z * v0[ks].z + v0[ks].w * v0[ks].w;
            ss += v1[ks].x * v1[ks].x + v1[ks].y * v1[ks].y
                + v1[ks].z * v1[ks].z + v1[ks].w * v1[ks].w;
        }
        ss += __shfl_xor(ss, 16, 64);    // lanes share row when m equal; sum quads
        ss += __shfl_xor(ss, 32, 64);
        const float inv = 1.0f / fmaxf(sqrtf(ss), 1e-12f);
#pragma unroll
        for (int ks = 0; ks < 4; ++ks) {
            bf16x8 v;
            v[0] = (bf16_t)(v0[ks].x * inv); v[1] = (bf16_t)(v0[ks].y * inv);
            v[2] = (bf16_t)(v0[ks].z * inv); v[3] = (bf16_t)(v0[ks].w * inv);
            v[4] = (bf16_t)(v1[ks].x * inv); v[5] = (bf16_t)(v1[ks].y * inv);
            v[6] = (bf16_t)(v1[ks].z * inv); v[7] = (bf16_t)(v1[ks].w * inv);
            af[s][ks] = v;
        }
    }

    f32x4 acc2[4][4];
#pragma unroll
    for (int s = 0; s < 4; ++s)
#pragma unroll
        for (int n2 = 0; n2 < 4; ++n2) acc2[s][n2] = (f32x4){0.f, 0.f, 0.f, 0.f};

#pragma unroll
    for (int p = 0; p < 8; ++p) {
        // ---- phase 1: h columns [p*32, p*32+32) for all 64 rows ----
#pragma unroll
        for (int h = 0; h < 2; ++h) {
            const int nt = p * 2 + h;
            const bf16_t* bp = W1t + (nt * 16 + m) * DIM_FEAT + quad * 8;
            bf16x8 bfr[4];
#pragma unroll
            for (int ks = 0; ks < 4; ++ks)
                bfr[ks] = *reinterpret_cast<const bf16x8*>(bp + ks * 32);
            const float bias = b1v[nt * 16 + m];
#pragma unroll
            for (int s = 0; s < 4; ++s) {
                f32x4 a1 = (f32x4){0.f, 0.f, 0.f, 0.f};
#pragma unroll
                for (int ks = 0; ks < 4; ++ks)
                    a1 = __builtin_amdgcn_mfma_f32_16x16x32_bf16(af[s][ks], bfr[ks], a1, 0, 0, 0);
#pragma unroll
                for (int i = 0; i < 4; ++i) {
                    float hv = a1[i] + bias;
                    hv = hv >= 0.f ? hv : 0.01f * hv;
                    hw[(s * 16 + quad * 4 + i) * HP + h * 16 + m] = (bf16_t)hv;
                }
            }
        }
        // ---- phase 2 partial K-step over k in [p*32, p*32+32) ----
        bf16x8 b2f[4];
#pragma unroll
        for (int n2 = 0; n2 < 4; ++n2)
            b2f[n2] = *reinterpret_cast<const bf16x8*>(W2t + (n2 * 16 + m) * HID + p * 32 + quad * 8);
#pragma unroll
        for (int s = 0; s < 4; ++s) {
            const bf16x8 a2 = *reinterpret_cast<const bf16x8*>(hw + (s * 16 + m) * HP + quad * 8);
#pragma unroll
            for (int n2 = 0; n2 < 4; ++n2)
                acc2[s][n2] = __builtin_amdgcn_mfma_f32_16x16x32_bf16(a2, b2f[n2], acc2[s][n2], 0, 0, 0);
        }
    }

    // ---- epilogue: bias + store ----
#pragma unroll
    for (int n2 = 0; n2 < 4; ++n2) {
        const float bias = b2v[n2 * 16 + m];
#pragma unroll
        for (int s = 0; s < 4; ++s) {
#pragma unroll
            for (int i = 0; i < 4; ++i)
                feature[(row_base + s * 16 + quad * 4 + i) * DIM_E + n2 * 16 + m]
                    = acc2[s][n2][i] + bias;
        }
    }
}

// ---------------------------------------------------------------------------
// K3: per-(b,g) element: gathers + 4 packed wave reductions + exp
// ---------------------------------------------------------------------------
__global__ __launch_bounds__(256) void loss_elem_kernel(
    const float* __restrict__ feature, const float* __restrict__ id_emb,
    const int* __restrict__ user_t, const int* __restrict__ item_t,
    const unsigned char* __restrict__ mask,
    float* __restrict__ s1, float* __restrict__ s2)
{
    const int wave = threadIdx.x >> 6;
    const int lane = threadIdx.x & 63;
    const int n = blockIdx.x * 4 + wave;
    const int b = n / GG;
    const int u   = user_t[n];
    const int it  = item_t[n];
    const int pos = item_t[b * GG];
    int fidx = it - NUM_USER;
    fidx = min(max(fidx, 0), NUM_ITEM - 1);

    const float fv = feature[(size_t)fidx * DIM_E + lane];
    const float ue = id_emb[(size_t)u * DIM_E + lane];
    const float pe = id_emb[(size_t)pos * DIM_E + lane];
    const float ae = mask[n] ? fv : id_emb[(size_t)it * DIM_E + lane];

    float rx = fv * fv;   // ||f||^2
    float ry = pe * pe;   // ||pe||^2
    float rz = pe * fv;   // pe . f
    float rw = ue * ae;   // ue . all_item_input
#pragma unroll
    for (int off = 32; off > 0; off >>= 1) {
        rx += __shfl_xor(rx, off, 64);
        ry += __shfl_xor(ry, off, 64);
        rz += __shfl_xor(rz, off, 64);
        rw += __shfl_xor(rw, off, 64);
    }
    if (lane == 0) {
        const float dot1 = rz / (fmaxf(sqrtf(rx), 1e-12f) * fmaxf(sqrtf(ry), 1e-12f));
        s1[n] = __expf(dot1 * 5.0f);   // 1/TEMP = 5
        s2[n] = __expf(rw * 5.0f);
    }
}

// ---------------------------------------------------------------------------
// K4: per-b softmax-style loss + block reduce -> 64 partials
// ---------------------------------------------------------------------------
__global__ __launch_bounds__(256) void loss_reduce_kernel(
    const float* __restrict__ s1, const float* __restrict__ s2,
    float* __restrict__ partials)
{
    const int b = blockIdx.x * 256 + threadIdx.x;  // 64*256 == 16384 exactly
    float tot1 = 0.f, tot2 = 0.f, p1 = 0.f, p2 = 0.f;
#pragma unroll
    for (int g = 0; g < GG; ++g) {
        const float a1 = s1[b * GG + g];
        const float a2 = s2[b * GG + g];
        if (g == 0) { p1 = a1; p2 = a2; }
        tot1 += a1; tot2 += a2;
    }
    const float l1 = -logf(p1 / (tot1 + 1e-8f) + 1e-8f);
    const float l2 = -logf(p2 / (tot2 + 1e-8f) + 1e-8f);
    float v = 0.5f * l1 + 0.5f * l2;
#pragma unroll
    for (int off = 32; off > 0; off >>= 1) v += __shfl_xor(v, off, 64);
    __shared__ float red[4];
    const int wave = threadIdx.x >> 6, lane = threadIdx.x & 63;
    if (lane == 0) red[wave] = v;
    __syncthreads();
    if (threadIdx.x == 0) partials[blockIdx.x] = red[0] + red[1] + red[2] + red[3];
}

__global__ __launch_bounds__(64) void final_kernel(
    const float* __restrict__ partials, float* __restrict__ out)
{
    float v = partials[threadIdx.x];
#pragma unroll
    for (int off = 32; off > 0; off >>= 1) v += __shfl_xor(v, off, 64);
    if (threadIdx.x == 0) out[0] = v * (1.0f / BATCH);
}

// ---------------------------------------------------------------------------
extern "C" void kernel_launch(void* const* d_in, const int* in_sizes, int n_in,
                              void* d_out, int out_size, void* d_ws, size_t ws_size,
                              hipStream_t stream)
{
    (void)in_sizes; (void)n_in; (void)out_size; (void)ws_size;
    const float* v_feat    = (const float*)d_in[0];
    const float* id_emb    = (const float*)d_in[1];
    const float* W1        = (const float*)d_in[2];
    const float* b1        = (const float*)d_in[3];
    const float* W2        = (const float*)d_in[4];
    const float* b2        = (const float*)d_in[5];
    const int*   user_t    = (const int*)d_in[6];
    const int*   item_t    = (const int*)d_in[7];
    const int*   rand_idx  = (const int*)d_in[8];

    char* ws = (char*)d_ws;
    bf16_t*        W1t      = (bf16_t*)(ws + 0);             // 65536
    bf16_t*        W2t      = (bf16_t*)(ws + 65536);         // 32768
    unsigned char* mask     = (unsigned char*)(ws + 98304);  // 278528
    float*         s1       = (float*)(ws + 376832);         // 1114112
    float*         s2       = (float*)(ws + 1490944);        // 1114112
    float*         partials = (float*)(ws + 2605056);        // 256
    float*         feature  = (float*)(ws + 2605312);        // 51.2 MB

    hipMemsetAsync(mask, 0, NN, stream);
    prep2_kernel<<<544, 256, 0, stream>>>(W1, W2, rand_idx, W1t, W2t, mask);
    encoder2_kernel<<<782, 256, 0, stream>>>(v_feat, W1t, b1, W2t, b2, feature);
    loss_elem_kernel<<<69632, 256, 0, stream>>>(feature, id_emb, user_t, item_t, mask, s1, s2);
    loss_reduce_kernel<<<64, 256, 0, stream>>>(s1, s2, partials);
    final_kernel<<<1, 64, 0, stream>>>(partials, (float*)d_out);
}

// Round 3
// 311.926 us; speedup vs baseline: 1.5429x; 1.1408x over previous
//
#include <hip/hip_runtime.h>
#include <hip/hip_bf16.h>

typedef __bf16 bf16_t;
typedef __bf16 bf16x8 __attribute__((ext_vector_type(8)));
typedef __bf16 bf16x4 __attribute__((ext_vector_type(4)));
typedef float f32x4 __attribute__((ext_vector_type(4)));

#define NUM_USER 200000
#define NUM_ITEM 200000
#define DIM_E 64
#define DIM_FEAT 128
#define HID 256
#define BATCH 16384
#define GG 17
#define NN (BATCH * GG)   // 278528
#define NREP 139264       // int(NN * 0.5)
#define HP 40             // LDS h-buffer pitch (32 cols used + 8 pad)

// ---------------------------------------------------------------------------
// K1: transpose + bf16-cast weights (fragments want N-major), scatter mask
// ---------------------------------------------------------------------------
__global__ __launch_bounds__(256) void prep2_kernel(
    const float* __restrict__ W1, const float* __restrict__ W2,
    const int* __restrict__ rand_index,
    bf16_t* __restrict__ W1t, bf16_t* __restrict__ W2t,
    unsigned char* __restrict__ mask)
{
    const int t = blockIdx.x * 256 + threadIdx.x;
    if (t < HID * DIM_FEAT) {            // W1t[n][k], n<256, k<128
        const int n = t >> 7, k = t & 127;
        W1t[t] = (bf16_t)W1[k * HID + n];
    }
    if (t < DIM_E * HID) {               // W2t[n][k], n<64, k<256
        const int n = t >> 8, k = t & 255;
        W2t[t] = (bf16_t)W2[k * DIM_E + n];
    }
    if (t < NREP) mask[rand_index[t]] = 1;
}

// ---------------------------------------------------------------------------
// K2: fused MFMA encoder v3. One wave = 64 rows (4 strips of 16).
//   Operand order SWAPPED vs v2: D = W_frag * act_frag, so the C-fragment's
//   4 regs are contiguous along n -> packed b64 LDS writes + dwordx4 C-stores.
//   l2norm fused; wave-private LDS; no barriers.
// ---------------------------------------------------------------------------
__global__ __launch_bounds__(256, 2) void encoder3_kernel(
    const float* __restrict__ vfeat,
    const bf16_t* __restrict__ W1t, const float* __restrict__ b1v,
    const bf16_t* __restrict__ W2t, const float* __restrict__ b2v,
    float* __restrict__ feature)
{
    const int wave = threadIdx.x >> 6;
    const int lane = threadIdx.x & 63;
    const int m    = lane & 15;   // item-row within strip (C col / B lane)
    const int quad = lane >> 4;
    const int wid  = blockIdx.x * 4 + wave;

    __shared__ bf16_t hlds[4][64 * HP];

    if (wid >= 3125) return;             // 3125 * 64 == 200000
    const size_t row_base = (size_t)wid * 64;
    bf16_t* hw = hlds[wave];

    // ---- activation fragments (normalized, bf16) for 4 strips ----
    bf16x8 af[4][4];
#pragma unroll
    for (int s = 0; s < 4; ++s) {
        const size_t row = row_base + s * 16 + m;
        const float* rp = vfeat + row * DIM_FEAT + quad * 8;
        float4 v0[4], v1[4];
#pragma unroll
        for (int ks = 0; ks < 4; ++ks) {
            v0[ks] = *reinterpret_cast<const float4*>(rp + ks * 32);
            v1[ks] = *reinterpret_cast<const float4*>(rp + ks * 32 + 4);
        }
        float ss = 0.f;
#pragma unroll
        for (int ks = 0; ks < 4; ++ks) {
            ss += v0[ks].x * v0[ks].x + v0[ks].y * v0[ks].y
                + v0[ks].z * v0[ks].z + v0[ks].w * v0[ks].w;
            ss += v1[ks].x * v1[ks].x + v1[ks].y * v1[ks].y
                + v1[ks].z * v1[ks].z + v1[ks].w * v1[ks].w;
        }
        ss += __shfl_xor(ss, 16, 64);
        ss += __shfl_xor(ss, 32, 64);
        const float inv = 1.0f / fmaxf(sqrtf(ss), 1e-12f);
#pragma unroll
        for (int ks = 0; ks < 4; ++ks) {
            bf16x8 v;
            v[0] = (bf16_t)(v0[ks].x * inv); v[1] = (bf16_t)(v0[ks].y * inv);
            v[2] = (bf16_t)(v0[ks].z * inv); v[3] = (bf16_t)(v0[ks].w * inv);
            v[4] = (bf16_t)(v1[ks].x * inv); v[5] = (bf16_t)(v1[ks].y * inv);
            v[6] = (bf16_t)(v1[ks].z * inv); v[7] = (bf16_t)(v1[ks].w * inv);
            af[s][ks] = v;
        }
    }

    f32x4 acc2[4][4];
#pragma unroll
    for (int s = 0; s < 4; ++s)
#pragma unroll
        for (int n2 = 0; n2 < 4; ++n2) acc2[s][n2] = (f32x4){0.f, 0.f, 0.f, 0.f};

#pragma unroll
    for (int p = 0; p < 8; ++p) {
        // ---- phase 1: hT fragments, cols [p*32, p*32+32), all 64 rows ----
#pragma unroll
        for (int h = 0; h < 2; ++h) {
            const int nt = p * 2 + h;
            const bf16_t* bp = W1t + (nt * 16 + m) * DIM_FEAT + quad * 8;
            bf16x8 bfr[4];
#pragma unroll
            for (int ks = 0; ks < 4; ++ks)
                bfr[ks] = *reinterpret_cast<const bf16x8*>(bp + ks * 32);
            const float4 bias1 = *reinterpret_cast<const float4*>(b1v + nt * 16 + quad * 4);
#pragma unroll
            for (int s = 0; s < 4; ++s) {
                f32x4 a1 = (f32x4){0.f, 0.f, 0.f, 0.f};
#pragma unroll
                for (int ks = 0; ks < 4; ++ks)   // A = W1 frag, B = act frag
                    a1 = __builtin_amdgcn_mfma_f32_16x16x32_bf16(bfr[ks], af[s][ks], a1, 0, 0, 0);
                // lane holds item-row m, h-cols nt*16+quad*4+i (i contiguous)
                bf16x4 hv4;
#pragma unroll
                for (int i = 0; i < 4; ++i) {
                    float hv = a1[i] + ((const float*)&bias1)[i];
                    hv = hv >= 0.f ? hv : 0.01f * hv;
                    hv4[i] = (bf16_t)hv;
                }
                *reinterpret_cast<bf16x4*>(hw + (s * 16 + m) * HP + h * 16 + quad * 4) = hv4;
            }
        }
        // ---- phase 2 partial K-step over k in [p*32, p*32+32) ----
        bf16x8 b2f[4];
#pragma unroll
        for (int n2 = 0; n2 < 4; ++n2)
            b2f[n2] = *reinterpret_cast<const bf16x8*>(W2t + (n2 * 16 + m) * HID + p * 32 + quad * 8);
#pragma unroll
        for (int s = 0; s < 4; ++s) {
            const bf16x8 a2 = *reinterpret_cast<const bf16x8*>(hw + (s * 16 + m) * HP + quad * 8);
#pragma unroll
            for (int n2 = 0; n2 < 4; ++n2)       // A = W2 frag, B = h frag
                acc2[s][n2] = __builtin_amdgcn_mfma_f32_16x16x32_bf16(b2f[n2], a2, acc2[s][n2], 0, 0, 0);
        }
    }

    // ---- epilogue: bias + packed float4 stores ----
#pragma unroll
    for (int n2 = 0; n2 < 4; ++n2) {
        const float4 bias2 = *reinterpret_cast<const float4*>(b2v + n2 * 16 + quad * 4);
#pragma unroll
        for (int s = 0; s < 4; ++s) {
            float4 o;
            o.x = acc2[s][n2][0] + bias2.x;
            o.y = acc2[s][n2][1] + bias2.y;
            o.z = acc2[s][n2][2] + bias2.z;
            o.w = acc2[s][n2][3] + bias2.w;
            *reinterpret_cast<float4*>(
                feature + (row_base + s * 16 + m) * DIM_E + n2 * 16 + quad * 4) = o;
        }
    }
}

// ---------------------------------------------------------------------------
// K3: loss elements v2 — 4 lanes per (b,g) element, 16 dims per lane.
//     2-level shuffle reduce instead of 6-level; 64 elements per block.
// ---------------------------------------------------------------------------
__global__ __launch_bounds__(256) void loss_elem2_kernel(
    const float* __restrict__ feature, const float* __restrict__ id_emb,
    const int* __restrict__ user_t, const int* __restrict__ item_t,
    const unsigned char* __restrict__ mask,
    float* __restrict__ s1, float* __restrict__ s2)
{
    const int kq = threadIdx.x & 3;          // k-quarter: dims [kq*16, kq*16+16)
    const int n  = blockIdx.x * 64 + (threadIdx.x >> 2);
    const int b  = n / GG;
    const int u   = user_t[n];
    const int it  = item_t[n];
    const int pos = item_t[b * GG];
    int fidx = it - NUM_USER;
    fidx = min(max(fidx, 0), NUM_ITEM - 1);

    const float4* fp  = reinterpret_cast<const float4*>(feature + (size_t)fidx * DIM_E) + kq * 4;
    const float4* up  = reinterpret_cast<const float4*>(id_emb + (size_t)u   * DIM_E) + kq * 4;
    const float4* pp  = reinterpret_cast<const float4*>(id_emb + (size_t)pos * DIM_E) + kq * 4;
    const float4* ap  = mask[n] ? fp
                      : reinterpret_cast<const float4*>(id_emb + (size_t)it * DIM_E) + kq * 4;

    float x = 0.f, y = 0.f, z = 0.f, w = 0.f;
#pragma unroll
    for (int j = 0; j < 4; ++j) {
        const float4 f = fp[j];
        const float4 p = pp[j];
        const float4 uu = up[j];
        const float4 a = ap[j];
        x += f.x * f.x + f.y * f.y + f.z * f.z + f.w * f.w;
        y += p.x * p.x + p.y * p.y + p.z * p.z + p.w * p.w;
        z += p.x * f.x + p.y * f.y + p.z * f.z + p.w * f.w;
        w += uu.x * a.x + uu.y * a.y + uu.z * a.z + uu.w * a.w;
    }
#pragma unroll
    for (int off = 1; off <= 2; off <<= 1) {
        x += __shfl_xor(x, off, 64);
        y += __shfl_xor(y, off, 64);
        z += __shfl_xor(z, off, 64);
        w += __shfl_xor(w, off, 64);
    }
    if (kq == 0) {
        const float dot1 = z / (fmaxf(sqrtf(x), 1e-12f) * fmaxf(sqrtf(y), 1e-12f));
        s1[n] = __expf(dot1 * 5.0f);   // 1/TEMP = 5
        s2[n] = __expf(w * 5.0f);
    }
}

// ---------------------------------------------------------------------------
// K4: per-b softmax-style loss + block reduce -> 64 partials
// ---------------------------------------------------------------------------
__global__ __launch_bounds__(256) void loss_reduce_kernel(
    const float* __restrict__ s1, const float* __restrict__ s2,
    float* __restrict__ partials)
{
    const int b = blockIdx.x * 256 + threadIdx.x;  // 64*256 == 16384 exactly
    float tot1 = 0.f, tot2 = 0.f, p1 = 0.f, p2 = 0.f;
#pragma unroll
    for (int g = 0; g < GG; ++g) {
        const float a1 = s1[b * GG + g];
        const float a2 = s2[b * GG + g];
        if (g == 0) { p1 = a1; p2 = a2; }
        tot1 += a1; tot2 += a2;
    }
    const float l1 = -logf(p1 / (tot1 + 1e-8f) + 1e-8f);
    const float l2 = -logf(p2 / (tot2 + 1e-8f) + 1e-8f);
    float v = 0.5f * l1 + 0.5f * l2;
#pragma unroll
    for (int off = 32; off > 0; off >>= 1) v += __shfl_xor(v, off, 64);
    __shared__ float red[4];
    const int wave = threadIdx.x >> 6, lane = threadIdx.x & 63;
    if (lane == 0) red[wave] = v;
    __syncthreads();
    if (threadIdx.x == 0) partials[blockIdx.x] = red[0] + red[1] + red[2] + red[3];
}

__global__ __launch_bounds__(64) void final_kernel(
    const float* __restrict__ partials, float* __restrict__ out)
{
    float v = partials[threadIdx.x];
#pragma unroll
    for (int off = 32; off > 0; off >>= 1) v += __shfl_xor(v, off, 64);
    if (threadIdx.x == 0) out[0] = v * (1.0f / BATCH);
}

// ---------------------------------------------------------------------------
extern "C" void kernel_launch(void* const* d_in, const int* in_sizes, int n_in,
                              void* d_out, int out_size, void* d_ws, size_t ws_size,
                              hipStream_t stream)
{
    (void)in_sizes; (void)n_in; (void)out_size; (void)ws_size;
    const float* v_feat    = (const float*)d_in[0];
    const float* id_emb    = (const float*)d_in[1];
    const float* W1        = (const float*)d_in[2];
    const float* b1        = (const float*)d_in[3];
    const float* W2        = (const float*)d_in[4];
    const float* b2        = (const float*)d_in[5];
    const int*   user_t    = (const int*)d_in[6];
    const int*   item_t    = (const int*)d_in[7];
    const int*   rand_idx  = (const int*)d_in[8];

    char* ws = (char*)d_ws;
    bf16_t*        W1t      = (bf16_t*)(ws + 0);             // 65536
    bf16_t*        W2t      = (bf16_t*)(ws + 65536);         // 32768
    unsigned char* mask     = (unsigned char*)(ws + 98304);  // 278528
    float*         s1       = (float*)(ws + 376832);         // 1114112
    float*         s2       = (float*)(ws + 1490944);        // 1114112
    float*         partials = (float*)(ws + 2605056);        // 256
    float*         feature  = (float*)(ws + 2605312);        // 51.2 MB

    hipMemsetAsync(mask, 0, NN, stream);
    prep2_kernel<<<544, 256, 0, stream>>>(W1, W2, rand_idx, W1t, W2t, mask);
    encoder3_kernel<<<782, 256, 0, stream>>>(v_feat, W1t, b1, W2t, b2, feature);
    loss_elem2_kernel<<<4352, 256, 0, stream>>>(feature, id_emb, user_t, item_t, mask, s1, s2);
    loss_reduce_kernel<<<64, 256, 0, stream>>>(s1, s2, partials);
    final_kernel<<<1, 64, 0, stream>>>(partials, (float*)d_out);
}